// Round 1
// baseline (1355.689 us; speedup 1.0000x reference)
//
#include <hip/hip_runtime.h>

// s_gcn fused kernel: out[n,c,t,w] = sum_k sum_v (W[k*64+c,:]·x[n,:,t,v] + b[k*64+c]) * A[k,v,w]
//
// Shapes (hardcoded from reference setup_inputs):
//   x: (16, 64, 2048, 25) f32   A: (3, 25, 25) f32   W: (192, 64) f32   b: (192,) f32
//   out: (16, 64, 2048, 25) f32
//
// Thread = one (c, t) pair. Block = 256 threads = 64 c-lanes x 4 t-values.
// A wave (64 lanes) covers all c for ONE t => LDS x-reads are same-address
// broadcasts (conflict-free); W reads are stride-1 across lanes (conflict-free).
// h[3][25] accumulators live in VGPRs; A applied from LDS in the epilogue.

#define K_NUM   3
#define C_IN    64
#define C_OUT   64
#define T_DIM   2048
#define V_DIM   25
#define N_DIM   16
#define T_BLK   4
#define O_DIM   (K_NUM * C_OUT)   // 192
#define CI_CHUNK 16

__global__ __launch_bounds__(256, 3)
void sgcn_fused(const float* __restrict__ x,
                const float* __restrict__ A,
                const float* __restrict__ W,
                const float* __restrict__ b,
                float* __restrict__ out) {
    __shared__ float xs[C_IN][T_BLK * V_DIM];   // [64][100]  25.6 KB
    __shared__ float ws[CI_CHUNK][O_DIM + 1];   // [16][193]  12.4 KB (pad kills write conflicts)
    __shared__ float as[K_NUM][V_DIM][V_DIM];   // [3][25][25] 7.5 KB

    const int tid = threadIdx.x;
    const int bid = blockIdx.x;
    const int nb  = bid / (T_DIM / T_BLK);
    const int tb  = bid % (T_DIM / T_BLK);
    const int t0  = tb * T_BLK;

    // ---- stage A (1875 floats, layout identical to global) ----
    for (int i = tid; i < K_NUM * V_DIM * V_DIM; i += 256)
        (&as[0][0][0])[i] = A[i];

    // ---- stage x tile: 64 rows x 100 contiguous floats, as float4 ----
    {
        const float4* xb = reinterpret_cast<const float4*>(
            x + (size_t)nb * C_IN * T_DIM * V_DIM + (size_t)t0 * V_DIM);
        // row stride in float4 units: T_DIM*V_DIM/4 = 12800
        for (int i = tid; i < C_IN * V_DIM; i += 256) {   // 1600 float4 loads
            const int ci = i / V_DIM;
            const int j4 = i % V_DIM;
            float4 val = xb[(size_t)ci * (T_DIM * V_DIM / 4) + j4];
            reinterpret_cast<float4*>(&xs[ci][0])[j4] = val;
        }
    }

    const int c  = tid & 63;   // lane = c  -> wave-wide broadcast on x reads
    const int tl = tid >> 6;   // which of the 4 t-values this thread owns

    float h0[V_DIM], h1[V_DIM], h2[V_DIM];
    const float b0 = b[c], b1 = b[C_OUT + c], b2 = b[2 * C_OUT + c];
    #pragma unroll
    for (int v = 0; v < V_DIM; ++v) { h0[v] = b0; h1[v] = b1; h2[v] = b2; }

    // ---- main loop: contract over c_in in chunks staged through LDS ----
    for (int chunk = 0; chunk < C_IN / CI_CHUNK; ++chunk) {
        __syncthreads();   // protects ws reuse (and first-iter: xs/as ready)
        // stage W chunk transposed: ws[ci_local][o] <- W[o][chunk*16+ci_local]
        for (int i = tid; i < CI_CHUNK * O_DIM; i += 256) {  // 3072 elems
            const int o  = i >> 4;
            const int cl = i & 15;
            ws[cl][o] = W[o * C_IN + chunk * CI_CHUNK + cl];
        }
        __syncthreads();

        #pragma unroll 4
        for (int cl = 0; cl < CI_CHUNK; ++cl) {
            const int ci = chunk * CI_CHUNK + cl;
            const float w0 = ws[cl][c];              // stride-1 across lanes
            const float w1 = ws[cl][C_OUT + c];
            const float w2 = ws[cl][2 * C_OUT + c];
            const float* xr = &xs[ci][tl * V_DIM];   // same addr across wave -> broadcast
            #pragma unroll
            for (int v = 0; v < V_DIM; ++v) {
                const float xv = xr[v];
                h0[v] = fmaf(w0, xv, h0[v]);
                h1[v] = fmaf(w1, xv, h1[v]);
                h2[v] = fmaf(w2, xv, h2[v]);
            }
        }
    }

    // ---- epilogue: out[w] = sum_k sum_v h[k][v] * A[k][v][w] ----
    float* op = out + (((size_t)nb * C_OUT + c) * T_DIM + (size_t)(t0 + tl)) * V_DIM;
    #pragma unroll 5
    for (int w = 0; w < V_DIM; ++w) {
        float acc = 0.f;
        #pragma unroll
        for (int v = 0; v < V_DIM; ++v) {
            acc = fmaf(h0[v], as[0][v][w], acc);
            acc = fmaf(h1[v], as[1][v][w], acc);
            acc = fmaf(h2[v], as[2][v][w], acc);
        }
        op[w] = acc;
    }
}

extern "C" void kernel_launch(void* const* d_in, const int* in_sizes, int n_in,
                              void* d_out, int out_size, void* d_ws, size_t ws_size,
                              hipStream_t stream) {
    const float* x = (const float*)d_in[0];
    const float* A = (const float*)d_in[1];
    const float* W = (const float*)d_in[2];
    const float* b = (const float*)d_in[3];
    float* out = (float*)d_out;

    dim3 grid(N_DIM * (T_DIM / T_BLK));   // 16 * 512 = 8192 blocks
    sgcn_fused<<<grid, 256, 0, stream>>>(x, A, W, b, out);
}

// Round 2
// 807.321 us; speedup vs baseline: 1.6792x; 1.6792x over previous
//
#include <hip/hip_runtime.h>

// s_gcn fused kernel: out[n,c,t,w] = sum_k sum_v (W[k*64+c,:]·x[n,:,t,v] + b[k*64+c]) * A[k,v,w]
//
// Shapes: x (16,64,2048,25) f32, A (3,25,25) f32, W (192,64) f32, b (192,) f32
// out (16,64,2048,25) f32
//
// Thread = one (c, t) pair. Block = 256 threads = 64 c-lanes x 4 t-values.
// Wave lanes = c => x LDS reads broadcast, W LDS reads stride-1.
// R2 fix: output staged in LDS (reusing xs) and written as coalesced float4
// rows — R1's per-thread scalar strided stores caused ~1.7 GB of partial-
// sector RMW traffic each way (8x write inflation).

#define K_NUM   3
#define C_IN    64
#define C_OUT   64
#define T_DIM   2048
#define V_DIM   25
#define N_DIM   16
#define T_BLK   4
#define O_DIM   (K_NUM * C_OUT)   // 192
#define CI_CHUNK 16

__global__ __launch_bounds__(256, 3)
void sgcn_fused(const float* __restrict__ x,
                const float* __restrict__ A,
                const float* __restrict__ W,
                const float* __restrict__ b,
                float* __restrict__ out) {
    __shared__ float xs[C_IN][T_BLK * V_DIM];    // [64][100] 25.6 KB (x tile, then out tile)
    __shared__ float ws[CI_CHUNK][O_DIM + 1];    // [16][193] 12.4 KB
    __shared__ float as[K_NUM][V_DIM][28];       // padded rows: 16B-aligned float4 reads, 8.4 KB

    const int tid = threadIdx.x;
    const int bid = blockIdx.x;
    const int nb  = bid / (T_DIM / T_BLK);
    const int tb  = bid % (T_DIM / T_BLK);
    const int t0  = tb * T_BLK;

    // ---- stage A with row padding 25->28 ----
    for (int i = tid; i < K_NUM * V_DIM * V_DIM; i += 256) {
        const int k = i / (V_DIM * V_DIM);
        const int r = (i / V_DIM) % V_DIM;
        const int w = i % V_DIM;
        as[k][r][w] = A[i];
    }

    // ---- stage x tile: 64 rows x 100 contiguous floats, as float4 ----
    {
        const float4* xb = reinterpret_cast<const float4*>(
            x + (size_t)nb * C_IN * T_DIM * V_DIM + (size_t)t0 * V_DIM);
        for (int i = tid; i < C_IN * V_DIM; i += 256) {   // 1600 float4 loads
            const int ci = i / V_DIM;
            const int j4 = i % V_DIM;
            float4 val = xb[(size_t)ci * (T_DIM * V_DIM / 4) + j4];
            reinterpret_cast<float4*>(&xs[ci][0])[j4] = val;
        }
    }

    const int c  = tid & 63;   // lane = c
    const int tl = tid >> 6;   // which of the 4 t-values

    float h0[V_DIM], h1[V_DIM], h2[V_DIM];
    const float b0 = b[c], b1 = b[C_OUT + c], b2 = b[2 * C_OUT + c];
    #pragma unroll
    for (int v = 0; v < V_DIM; ++v) { h0[v] = b0; h1[v] = b1; h2[v] = b2; }

    // ---- main loop: contract over c_in in chunks staged through LDS ----
    for (int chunk = 0; chunk < C_IN / CI_CHUNK; ++chunk) {
        __syncthreads();
        for (int i = tid; i < CI_CHUNK * O_DIM; i += 256) {
            const int o  = i >> 4;
            const int cl = i & 15;
            ws[cl][o] = W[o * C_IN + chunk * CI_CHUNK + cl];
        }
        __syncthreads();

        #pragma unroll 4
        for (int cl = 0; cl < CI_CHUNK; ++cl) {
            const int ci = chunk * CI_CHUNK + cl;
            const float w0 = ws[cl][c];
            const float w1 = ws[cl][C_OUT + c];
            const float w2 = ws[cl][2 * C_OUT + c];
            const float* xr = &xs[ci][tl * V_DIM];
            #pragma unroll
            for (int v = 0; v < V_DIM; ++v) {
                const float xv = xr[v];
                h0[v] = fmaf(w0, xv, h0[v]);
                h1[v] = fmaf(w1, xv, h1[v]);
                h2[v] = fmaf(w2, xv, h2[v]);
            }
        }
    }

    // ---- epilogue: acc[w] = sum_k sum_v h[k][v] * A[k][v][w], float4 A reads ----
    float acc[V_DIM];
    #pragma unroll
    for (int w = 0; w < V_DIM; ++w) acc[w] = 0.f;

    #pragma unroll 5
    for (int v = 0; v < V_DIM; ++v) {
        const float4* a0 = reinterpret_cast<const float4*>(&as[0][v][0]);
        const float4* a1 = reinterpret_cast<const float4*>(&as[1][v][0]);
        const float4* a2 = reinterpret_cast<const float4*>(&as[2][v][0]);
        const float hv0 = h0[v], hv1 = h1[v], hv2 = h2[v];
        #pragma unroll
        for (int q = 0; q < 6; ++q) {
            const float4 A0 = a0[q], A1 = a1[q], A2 = a2[q];
            acc[4*q+0] = fmaf(hv0, A0.x, fmaf(hv1, A1.x, fmaf(hv2, A2.x, acc[4*q+0])));
            acc[4*q+1] = fmaf(hv0, A0.y, fmaf(hv1, A1.y, fmaf(hv2, A2.y, acc[4*q+1])));
            acc[4*q+2] = fmaf(hv0, A0.z, fmaf(hv1, A1.z, fmaf(hv2, A2.z, acc[4*q+2])));
            acc[4*q+3] = fmaf(hv0, A0.w, fmaf(hv1, A1.w, fmaf(hv2, A2.w, acc[4*q+3])));
        }
        acc[24] = fmaf(hv0, as[0][v][24], fmaf(hv1, as[1][v][24], fmaf(hv2, as[2][v][24], acc[24])));
    }

    // ---- stage out tile into xs (reuse), then coalesced float4 global write ----
    __syncthreads();   // all waves done reading xs
    #pragma unroll
    for (int w = 0; w < V_DIM; ++w)
        xs[c][tl * V_DIM + w] = acc[w];
    __syncthreads();

    {
        float4* ob = reinterpret_cast<float4*>(
            out + (size_t)nb * C_IN * T_DIM * V_DIM + (size_t)t0 * V_DIM);
        for (int i = tid; i < C_IN * V_DIM; i += 256) {   // 1600 float4 stores
            const int ci = i / V_DIM;
            const int j4 = i % V_DIM;
            ob[(size_t)ci * (T_DIM * V_DIM / 4) + j4] =
                reinterpret_cast<const float4*>(&xs[ci][0])[j4];
        }
    }
}

extern "C" void kernel_launch(void* const* d_in, const int* in_sizes, int n_in,
                              void* d_out, int out_size, void* d_ws, size_t ws_size,
                              hipStream_t stream) {
    const float* x = (const float*)d_in[0];
    const float* A = (const float*)d_in[1];
    const float* W = (const float*)d_in[2];
    const float* b = (const float*)d_in[3];
    float* out = (float*)d_out;

    dim3 grid(N_DIM * (T_DIM / T_BLK));   // 8192 blocks
    sgcn_fused<<<grid, 256, 0, stream>>>(x, A, W, b, out);
}

// Round 4
// 592.901 us; speedup vs baseline: 2.2865x; 1.3616x over previous
//
#include <hip/hip_runtime.h>

// s_gcn fused: out[n,c,t,w] = sum_k sum_v (W[k*64+c,:]·x[n,:,t,v] + b[k*64+c]) * A[k,v,w]
// x (16,64,2048,25) f32, A (3,25,25), W (192,64), b (192,), out (16,64,2048,25)
//
// Thread = (c, t) pair; block = 64 c-lanes x 4 t. Wave lane = c.
// R3: (a) main-loop LDS vectorized: x row read as 7 ds_read_b128 broadcasts
//     (aligned window, compile-time shift per tl), W as one float4/lane
//     -> 8 LDS instrs/ci instead of 28 (LDS pipe was ~60-80% of R2's time).
//     (b) output tile written with nontemporal float4 stores (bypass L2
//     partial-line RMW churn that inflated WRITE_SIZE 11x).
// R4: fix compile error — __builtin_nontemporal_store needs a NATIVE vector
//     type, not HIP's float4 class; use ext_vector_type(4) alias.

#define K_NUM   3
#define C_IN    64
#define C_OUT   64
#define T_DIM   2048
#define V_DIM   25
#define N_DIM   16
#define T_BLK   4
#define O_DIM   (K_NUM * C_OUT)
#define CI_CHUNK 16

typedef float nfloat4 __attribute__((ext_vector_type(4)));

// Inner ci-chunk: TL = wave's t-slot (uniform). x floats [TL*25, TL*25+25) are
// read as 7 aligned float4s starting at float4 index W4B with shift SH.
template<int TL>
__device__ __forceinline__ void main_chunk(const float4* __restrict__ xs4,  // [64][25]
                                           const float4* __restrict__ ws4,  // [16][64]
                                           int ci0, int c,
                                           float* __restrict__ h0,
                                           float* __restrict__ h1,
                                           float* __restrict__ h2) {
    constexpr int SH  = (TL * V_DIM) & 3;   // 0,1,2,3
    constexpr int W4B = (TL * V_DIM) >> 2;  // 0,6,12,18
    #pragma unroll 2
    for (int cl = 0; cl < CI_CHUNK; ++cl) {
        const float4 w = ws4[cl * C_IN + c];                 // stride-16B lanes, conflict-free
        const float4* xw = xs4 + (ci0 + cl) * (V_DIM) + W4B; // broadcast reads
        float xv[V_DIM];
        #pragma unroll
        for (int j = 0; j < 7; ++j) {
            const float4 q = xw[j];
            const int bx = j * 4 - SH;
            if (bx + 0 >= 0 && bx + 0 < V_DIM) xv[bx + 0] = q.x;
            if (bx + 1 >= 0 && bx + 1 < V_DIM) xv[bx + 1] = q.y;
            if (bx + 2 >= 0 && bx + 2 < V_DIM) xv[bx + 2] = q.z;
            if (bx + 3 >= 0 && bx + 3 < V_DIM) xv[bx + 3] = q.w;
        }
        #pragma unroll
        for (int v = 0; v < V_DIM; ++v) {
            h0[v] = fmaf(w.x, xv[v], h0[v]);
            h1[v] = fmaf(w.y, xv[v], h1[v]);
            h2[v] = fmaf(w.z, xv[v], h2[v]);
        }
    }
}

__global__ __launch_bounds__(256, 3)
void sgcn_fused(const float* __restrict__ x,
                const float* __restrict__ A,
                const float* __restrict__ W,
                const float* __restrict__ b,
                float* __restrict__ out) {
    __shared__ __align__(16) float xs[C_IN][T_BLK * V_DIM];  // [64][100] 25.6 KB
    __shared__ float4 ws4[CI_CHUNK * C_IN];                  // 16 KB: {w0,w1,w2,-} per (cl,c)
    __shared__ __align__(16) float as[K_NUM][V_DIM][28];     // 8.4 KB, float4-aligned rows

    const int tid = threadIdx.x;
    const int bid = blockIdx.x;
    const int nb  = bid / (T_DIM / T_BLK);
    const int tb  = bid % (T_DIM / T_BLK);
    const int t0  = tb * T_BLK;

    // ---- stage A (padded rows) ----
    for (int i = tid; i < K_NUM * V_DIM * V_DIM; i += 256) {
        const int k = i / (V_DIM * V_DIM);
        const int r = (i / V_DIM) % V_DIM;
        const int w = i % V_DIM;
        as[k][r][w] = A[i];
    }

    // ---- stage x tile: 64 rows x 25 float4, coalesced ----
    {
        const float4* xb = reinterpret_cast<const float4*>(
            x + (size_t)nb * C_IN * T_DIM * V_DIM + (size_t)t0 * V_DIM);
        for (int i = tid; i < C_IN * V_DIM; i += 256) {   // 1600 float4
            const int ci = i / V_DIM;
            const int j4 = i % V_DIM;
            float4 val = xb[(size_t)ci * (T_DIM * V_DIM / 4) + j4];
            reinterpret_cast<float4*>(&xs[ci][0])[j4] = val;
        }
    }

    const int c  = tid & 63;
    const int tl = tid >> 6;

    float h0[V_DIM], h1[V_DIM], h2[V_DIM];
    const float b0 = b[c], b1 = b[C_OUT + c], b2 = b[2 * C_OUT + c];
    #pragma unroll
    for (int v = 0; v < V_DIM; ++v) { h0[v] = b0; h1[v] = b1; h2[v] = b2; }

    const float4* xs4 = reinterpret_cast<const float4*>(&xs[0][0]);

    // ---- main loop over ci chunks ----
    for (int chunk = 0; chunk < C_IN / CI_CHUNK; ++chunk) {
        __syncthreads();
        // stage W chunk as packed float4 {W[c][cc], W[64+c][cc], W[128+c][cc], 0}
        for (int i = tid; i < CI_CHUNK * C_IN; i += 256) {   // 1024 float4
            const int cl = i >> 6;
            const int cc = chunk * CI_CHUNK + cl;
            const int lc = i & 63;
            ws4[i] = make_float4(W[(0 * C_OUT + lc) * C_IN + cc],
                                 W[(1 * C_OUT + lc) * C_IN + cc],
                                 W[(2 * C_OUT + lc) * C_IN + cc],
                                 0.f);
        }
        __syncthreads();

        const int ci0 = chunk * CI_CHUNK;
        if      (tl == 0) main_chunk<0>(xs4, ws4, ci0, c, h0, h1, h2);
        else if (tl == 1) main_chunk<1>(xs4, ws4, ci0, c, h0, h1, h2);
        else if (tl == 2) main_chunk<2>(xs4, ws4, ci0, c, h0, h1, h2);
        else              main_chunk<3>(xs4, ws4, ci0, c, h0, h1, h2);
    }

    // ---- epilogue: acc[w] = sum_k sum_v h[k][v] * A[k][v][w] ----
    float acc[V_DIM];
    #pragma unroll
    for (int w = 0; w < V_DIM; ++w) acc[w] = 0.f;

    #pragma unroll 5
    for (int v = 0; v < V_DIM; ++v) {
        const float4* a0 = reinterpret_cast<const float4*>(&as[0][v][0]);
        const float4* a1 = reinterpret_cast<const float4*>(&as[1][v][0]);
        const float4* a2 = reinterpret_cast<const float4*>(&as[2][v][0]);
        const float hv0 = h0[v], hv1 = h1[v], hv2 = h2[v];
        #pragma unroll
        for (int q = 0; q < 6; ++q) {
            const float4 A0 = a0[q], A1 = a1[q], A2 = a2[q];
            acc[4*q+0] = fmaf(hv0, A0.x, fmaf(hv1, A1.x, fmaf(hv2, A2.x, acc[4*q+0])));
            acc[4*q+1] = fmaf(hv0, A0.y, fmaf(hv1, A1.y, fmaf(hv2, A2.y, acc[4*q+1])));
            acc[4*q+2] = fmaf(hv0, A0.z, fmaf(hv1, A1.z, fmaf(hv2, A2.z, acc[4*q+2])));
            acc[4*q+3] = fmaf(hv0, A0.w, fmaf(hv1, A1.w, fmaf(hv2, A2.w, acc[4*q+3])));
        }
        acc[24] = fmaf(hv0, as[0][v][24], fmaf(hv1, as[1][v][24], fmaf(hv2, as[2][v][24], acc[24])));
    }

    // ---- stage out tile into xs, then nontemporal coalesced float4 write ----
    __syncthreads();
    #pragma unroll
    for (int w = 0; w < V_DIM; ++w)
        xs[c][tl * V_DIM + w] = acc[w];
    __syncthreads();

    {
        nfloat4* ob = reinterpret_cast<nfloat4*>(
            out + (size_t)nb * C_IN * T_DIM * V_DIM + (size_t)t0 * V_DIM);
        const nfloat4* xsn = reinterpret_cast<const nfloat4*>(&xs[0][0]);
        for (int i = tid; i < C_IN * V_DIM; i += 256) {   // 1600 float4
            const int ci = i / V_DIM;
            const int j4 = i % V_DIM;
            const nfloat4 val = xsn[ci * V_DIM + j4];
            __builtin_nontemporal_store(val, &ob[(size_t)ci * (T_DIM * V_DIM / 4) + j4]);
        }
    }
}

extern "C" void kernel_launch(void* const* d_in, const int* in_sizes, int n_in,
                              void* d_out, int out_size, void* d_ws, size_t ws_size,
                              hipStream_t stream) {
    const float* x = (const float*)d_in[0];
    const float* A = (const float*)d_in[1];
    const float* W = (const float*)d_in[2];
    const float* b = (const float*)d_in[3];
    float* out = (float*)d_out;

    dim3 grid(N_DIM * (T_DIM / T_BLK));   // 8192 blocks
    sgcn_fused<<<grid, 256, 0, stream>>>(x, A, W, b, out);
}